// Round 6
// baseline (272.981 us; speedup 1.0000x reference)
//
#include <hip/hip_runtime.h>
#include <cstdint>

#define NTOK 32768
#define DDIM 256
#define KCB  4096
#define NSA 4            // n-splits in pass A (1024 codes per block)
#define NST 16           // n-splits in tier-2 (256 codes per block)
#define XCAP 16384       // max flagged tokens (safety cap; expect ~2%)
#define MARGIN_U 0.18f   // on u = dot - e2/2 + 512 scale (s-scale 0.36)

typedef _Float16 half8 __attribute__((ext_vector_type(8)));
typedef float f32x4 __attribute__((ext_vector_type(4)));
typedef unsigned short ushort_t;

// ---------------------------------------------------------------------------
// helpers
// ---------------------------------------------------------------------------
__device__ __forceinline__ ushort_t f2h(float f, float& back) {
    _Float16 h = (_Float16)f;
    back = (float)h;
    union { _Float16 h; ushort_t u; } c; c.h = h; return c.u;
}
__device__ __forceinline__ short h2s(_Float16 h) {
    union { _Float16 h; short s; } c; c.h = h; return c.s;
}
__device__ __forceinline__ void gload_lds16(const void* g, void* l) {
    __builtin_amdgcn_global_load_lds(
        (const __attribute__((address_space(1))) void*)g,
        (__attribute__((address_space(3))) void*)l, 16, 0, 0);
}
template <bool FIRST>
__device__ __forceinline__ void frag_mfma(const char* Ab, const char* Bb, f32x4 (&acc)[4][4]) {
    half8 af[4], bf[4];
#pragma unroll
    for (int i = 0; i < 4; ++i) af[i] = *(const half8*)(Ab + i * 1024);
#pragma unroll
    for (int j = 0; j < 4; ++j) bf[j] = *(const half8*)(Bb + j * 1024);
#pragma unroll
    for (int i = 0; i < 4; ++i)
#pragma unroll
        for (int j = 0; j < 4; ++j) {
            if (FIRST)
                acc[i][j] = __builtin_amdgcn_mfma_f32_16x16x32_f16(
                    af[i], bf[j], (f32x4){0.f, 0.f, 0.f, 0.f}, 0, 0, 0);
            else
                acc[i][j] = __builtin_amdgcn_mfma_f32_16x16x32_f16(
                    af[i], bf[j], acc[i][j], 0, 0, 0);
        }
}
// A-operand from registers (pass_a round-6): only B read from LDS
template <bool FIRST>
__device__ __forceinline__ void frag_mfma_reg(const half8 (&af)[4], const char* Bb,
                                              f32x4 (&acc)[4][4]) {
    half8 bf[4];
#pragma unroll
    for (int j = 0; j < 4; ++j) bf[j] = *(const half8*)(Bb + j * 1024);
#pragma unroll
    for (int i = 0; i < 4; ++i)
#pragma unroll
        for (int j = 0; j < 4; ++j) {
            if (FIRST)
                acc[i][j] = __builtin_amdgcn_mfma_f32_16x16x32_f16(
                    af[i], bf[j], (f32x4){0.f, 0.f, 0.f, 0.f}, 0, 0, 0);
            else
                acc[i][j] = __builtin_amdgcn_mfma_f32_16x16x32_f16(
                    af[i], bf[j], acc[i][j], 0, 0, 0);
        }
}

// ---------------------------------------------------------------------------
// convert embed -> f16 hi/lo + cc[k] = 512 - 0.5*e2[k]  (wave per row)
// block 0 zeroes count (replaces the hipMemsetAsync dispatch)
// ---------------------------------------------------------------------------
__global__ __launch_bounds__(256) void vq_convert_e(
        const float* __restrict__ embed, ushort_t* __restrict__ hi,
        ushort_t* __restrict__ lo, float* __restrict__ cc,
        int* __restrict__ count) {
    if (blockIdx.x == 0 && threadIdx.x == 0) *count = 0;
    int row = blockIdx.x * 4 + (threadIdx.x >> 6);
    int lane = threadIdx.x & 63;
    size_t off = (size_t)row * DDIM + lane * 4;
    float4 v = *(const float4*)(embed + off);
    float bx, by, bz, bw;
    ushort4 h, l;
    h.x = f2h(v.x, bx); h.y = f2h(v.y, by); h.z = f2h(v.z, bz); h.w = f2h(v.w, bw);
    float t;
    l.x = f2h(v.x - bx, t); l.y = f2h(v.y - by, t);
    l.z = f2h(v.z - bz, t); l.w = f2h(v.w - bw, t);
    *(ushort4*)(hi + off) = h;
    *(ushort4*)(lo + off) = l;
    float s = v.x * v.x + v.y * v.y + v.z * v.z + v.w * v.w;
#pragma unroll
    for (int o = 1; o < 64; o <<= 1) s += __shfl_xor(s, o, 64);
    if (lane == 0) cc[row] = 512.f - 0.5f * s;
}

// ---------------------------------------------------------------------------
// Pass A (round-6 restructure): 128 tokens x 1024 codes.
//   A: staged to LDS once (swizzled, as round-1) -> read into REGISTERS
//      (Ar[8][4] half8 = full 64-row x 256-dim wave slice), LDS region then
//      reused as a 4-deep B ring (32KB, aliased union).
//   K-loop: counted-vmcnt barrier (s_waitcnt vmcnt(2); s_barrier) with
//      stageB(it+2) -> issue-to-consume distance of 2 barriers; loads stay in
//      flight across barriers (T3/T4). Full vmcnt(0) drain only at kk==7.
//   LDS traffic: 2.56 -> 1.73 MB/block; per-iter reads 8 -> 4 x b128.
//   MFMA order/operands identical to round-5 -> bit-identical output.
// ---------------------------------------------------------------------------
__global__ __launch_bounds__(256, 2) void vq_pass_a(
        const float* __restrict__ x, const ushort_t* __restrict__ eh,
        const float* __restrict__ cc,
        float* __restrict__ gv1, int* __restrict__ gi1, float* __restrict__ gv2) {
    __shared__ union U {
        struct { short A[8][128][32]; } a;   // 64KB A staging (consumed to regs)
        struct { short B[4][128][32]; } b;   // 32KB B ring (aliases A region)
        struct { float v1[128][2]; int i1[128][2]; float v2[128][2]; } r;
    } sh;
    const int tid = threadIdx.x;
    const int m0 = blockIdx.x * 128;
    const int kbase = blockIdx.y * (KCB / NSA);

    const int lane = tid & 63, wv = tid >> 6, wr = wv >> 1, wc = wv & 1;
    const int L15 = lane & 15, quad = lane >> 4;

    const int ca0 = tid, ca1 = 256 + tid;
    const int row0 = ca0 >> 2, q0 = (ca0 & 3) ^ ((ca0 >> 3) & 3);
    const int row1 = ca1 >> 2, q1 = (ca1 & 3) ^ ((ca1 >> 3) & 3);

    auto stageB = [&](int it) {
        int nt = it >> 3, kk = it & 7;
        short* dst = &sh.b.B[it & 3][0][0];
        int n0 = kbase + nt * 128;
        gload_lds16(eh + (size_t)(n0 + row0) * DDIM + kk * 32 + q0 * 8, dst + ca0 * 8);
        gload_lds16(eh + (size_t)(n0 + row1) * DDIM + kk * 32 + q1 * 8, dst + ca1 * 8);
    };

    // ---- stage A: x fp32 -> f16, once per block (swizzled layout) ----
    {
        const int fr = tid >> 6;      // row offset 0..3
        const int f = tid & 63;       // float4 index within row
        const int akk = f >> 3;       // kk block 0..7
        const int rsw = akk & 1;      // row-bit swizzle for this kk block
        short* Aflat = &sh.a.A[0][0][0];
#pragma unroll 4
        for (int s = 0; s < 32; ++s) {
            int row = s * 4 + fr;
            float4 v = *(const float4*)(x + (size_t)(m0 + row) * DDIM + f * 4);
            short4 pk = { h2s((_Float16)v.x), h2s((_Float16)v.y),
                          h2s((_Float16)v.z), h2s((_Float16)v.w) };
            int qp = ((f >> 1) & 3) ^ ((row >> 1) & 3);
            int rowp = row ^ rsw;
            *(short4*)(Aflat + akk * 4096 + rowp * 32 + qp * 8 + (f & 1) * 4) = pk;
        }
    }
    __syncthreads();

    // ---- A slice -> registers (same swizzled read addressing as round-5) ----
    const int chn = (quad ^ ((L15 >> 1) & 3)) * 16;
    const int aoffE = (wr * 64 + L15) * 64 + chn;
    const char* Abase = (const char*)&sh.a.A[0][0][0];
    const char* Ab0e = Abase + aoffE;
    const char* Ab0o = Abase + (aoffE ^ 64);       // kk odd: row-bit flipped
    half8 Ar[8][4];
#pragma unroll
    for (int k2 = 0; k2 < 8; ++k2) {
        const char* Ab = ((k2 & 1) ? Ab0o : Ab0e) + k2 * 8192;
#pragma unroll
        for (int i = 0; i < 4; ++i) Ar[k2][i] = *(const half8*)(Ab + i * 1024);
    }
    __syncthreads();                  // A fully consumed; B ring may overwrite

    stageB(0);
    stageB(1);

    const char* Bb0 = (const char*)&sh.b.B[0][0][0] + (wc * 64 + L15) * 64 + chn;

    float v1p[16], v2p[16];
#pragma unroll
    for (int s = 0; s < 16; ++s) { v1p[s] = -3.4e38f; v2p[s] = -3.4e38f; }

#pragma unroll 1
    for (int nt = 0; nt < 8; ++nt) {
        f32x4 acc[4][4];
        float cc0, cc1, cc2, cc3;
#pragma unroll
        for (int kk = 0; kk < 8; ++kk) {
            const int it = nt * 8 + kk;
            // counted-vmcnt barrier: buffer(it) staged 2 barriers ago; the only
            // strictly-newer VMEM ops are stage(it+1)'s 2 loads -> vmcnt(2).
            // (cc loads are older than those -> also forced complete. FIFO.)
            if (kk == 7)
                asm volatile("s_waitcnt vmcnt(0)\n\ts_barrier" ::: "memory");
            else
                asm volatile("s_waitcnt vmcnt(2)\n\ts_barrier" ::: "memory");
            if (it + 2 < 64) stageB(it + 2);
            if (kk == 1) {   // prefetch cc, consumed at epilogue (7 iters later)
                const float* cb = cc + kbase + nt * 128 + wc * 64 + L15;
                cc0 = cb[0]; cc1 = cb[16]; cc2 = cb[32]; cc3 = cb[48];
            }
            const char* Bb = Bb0 + (it & 3) * 8192;
            if (kk == 0) frag_mfma_reg<true>(Ar[0], Bb, acc);
            else if (kk == 1) frag_mfma_reg<false>(Ar[1], Bb, acc);
            else if (kk == 2) frag_mfma_reg<false>(Ar[2], Bb, acc);
            else if (kk == 3) frag_mfma_reg<false>(Ar[3], Bb, acc);
            else if (kk == 4) frag_mfma_reg<false>(Ar[4], Bb, acc);
            else if (kk == 5) frag_mfma_reg<false>(Ar[5], Bb, acc);
            else if (kk == 6) frag_mfma_reg<false>(Ar[6], Bb, acc);
            else              frag_mfma_reg<false>(Ar[7], Bb, acc);
        }
        // packed top-2 epilogue (maximize u)
#pragma unroll
        for (int i = 0; i < 4; ++i)
#pragma unroll
            for (int r = 0; r < 4; ++r) {
                const int slot = i * 4 + r;
#pragma unroll
                for (int j = 0; j < 4; ++j) {
                    float ccj = (j == 0) ? cc0 : (j == 1) ? cc1 : (j == 2) ? cc2 : cc3;
                    float u = acc[i][j][r] + ccj;
                    unsigned linv = 31u - (unsigned)(nt * 4 + j);
                    float p = __uint_as_float((__float_as_uint(u) & ~31u) | linv);
                    float tmin = fminf(v1p[slot], p);
                    v1p[slot] = fmaxf(v1p[slot], p);
                    v2p[slot] = fmaxf(v2p[slot], tmin);
                }
            }
    }

    __syncthreads();
    // unpack + cross-lane butterfly + cross-wc merge
#pragma unroll
    for (int i = 0; i < 4; ++i)
#pragma unroll
        for (int r = 0; r < 4; ++r) {
            const int slot = i * 4 + r;
            unsigned b1 = __float_as_uint(v1p[slot]);
            int l1 = 31 - (int)(b1 & 31u);
            float a1 = v1p[slot];
            int ai = kbase + (l1 >> 2) * 128 + wc * 64 + (l1 & 3) * 16 + L15;
            float a2 = v2p[slot];
#pragma unroll
            for (int off = 1; off < 16; off <<= 1) {
                float o1 = __shfl_xor(a1, off, 64);
                int oi = __shfl_xor(ai, off, 64);
                float o2 = __shfl_xor(a2, off, 64);
                if (o1 > a1 || (o1 == a1 && oi < ai)) {
                    a2 = fmaxf(a1, o2); a1 = o1; ai = oi;
                } else {
                    a2 = fmaxf(a2, o1);
                }
            }
            if (L15 == 0) {
                int lr = wr * 64 + i * 16 + quad * 4 + r;
                sh.r.v1[lr][wc] = a1; sh.r.i1[lr][wc] = ai; sh.r.v2[lr][wc] = a2;
            }
        }
    __syncthreads();
    if (tid < 128) {
        float av1 = sh.r.v1[tid][0]; int ai1 = sh.r.i1[tid][0]; float av2 = sh.r.v2[tid][0];
        float bv1 = sh.r.v1[tid][1]; int bi1 = sh.r.i1[tid][1]; float bv2 = sh.r.v2[tid][1];
        float o1, o2; int oi;
        if (bv1 > av1 || (bv1 == av1 && bi1 < ai1)) { o1 = bv1; oi = bi1; o2 = fmaxf(av1, bv2); }
        else { o1 = av1; oi = ai1; o2 = fmaxf(av2, bv1); }
        size_t o = (size_t)(m0 + tid) * NSA + blockIdx.y;
        gv1[o] = o1; gi1[o] = oi; gv2[o] = o2;
    }
}

// ---------------------------------------------------------------------------
// merge NSA slices per token; gather clear winners; flag small-gap tokens
// AND compact-convert their x row to f16 hi/lo in the same pass
// (one wave per token, 4 tokens per wave via grid-stride; grid 2048)
// ---------------------------------------------------------------------------
__global__ __launch_bounds__(256) void vq_merge_gather(
        const float* __restrict__ gv1, const int* __restrict__ gi1,
        const float* __restrict__ gv2, const float* __restrict__ embed,
        const float* __restrict__ x,
        float* __restrict__ out, int* __restrict__ wl, int* __restrict__ count,
        ushort_t* __restrict__ xhc, ushort_t* __restrict__ xlc) {
    const int wave = threadIdx.x >> 6, lane = threadIdx.x & 63;
#pragma unroll 1
    for (int t = blockIdx.x * 4 + wave; t < NTOK; t += 8192) {
        float v1 = -3.4e38f, v2 = -3.4e38f; int i1 = 0x7fffffff;
        if (lane < NSA) {
            size_t o = (size_t)t * NSA + lane;
            v1 = gv1[o]; i1 = gi1[o]; v2 = gv2[o];
        }
#pragma unroll
        for (int off = 1; off < NSA; off <<= 1) {
            float o1 = __shfl_xor(v1, off, 64);
            int oi = __shfl_xor(i1, off, 64);
            float o2 = __shfl_xor(v2, off, 64);
            if (o1 > v1 || (o1 == v1 && oi < i1)) { v2 = fmaxf(v1, o2); v1 = o1; i1 = oi; }
            else v2 = fmaxf(v2, o1);
        }
        int flag = __shfl((v1 - v2 < MARGIN_U) ? 1 : 0, 0, 64);
        int idx = __shfl(i1, 0, 64);
        int p = 0x7fffffff;
        if (flag && lane == 0) p = atomicAdd(count, 1);
        p = __shfl(p, 0, 64);
        if (flag && p < XCAP) {
            // compact-convert this token's x row at slot p
            float4 v = *(const float4*)(x + (size_t)t * DDIM + lane * 4);
            float bx, by, bz, bw;
            ushort4 h, l;
            h.x = f2h(v.x, bx); h.y = f2h(v.y, by); h.z = f2h(v.z, bz); h.w = f2h(v.w, bw);
            float tt;
            l.x = f2h(v.x - bx, tt); l.y = f2h(v.y - by, tt);
            l.z = f2h(v.z - bz, tt); l.w = f2h(v.w - bw, tt);
            size_t off2 = (size_t)p * DDIM + lane * 4;
            *(ushort4*)(xhc + off2) = h;
            *(ushort4*)(xlc + off2) = l;
            if (lane == 0) wl[p] = t;
        } else {
            const float4* src = (const float4*)(embed + (size_t)idx * DDIM);
            float4* dst = (float4*)(out + (size_t)t * DDIM);
            dst[lane] = src[lane];
        }
    }
}

// ---------------------------------------------------------------------------
// Tier-2: fused 3-product f16 MFMA rescore over compacted flagged tokens.
// acc = xh*eh + xh*el + xl*eh  (all into one accumulator), so per kk-chunk
// stage all 4 tiles (32KB) once, double-buffered, 48 MFMA per barrier window.
// Grid (XCAP/128, NST). Maximize u = dot + cc.
// ---------------------------------------------------------------------------
__global__ __launch_bounds__(256, 2) void vq_rescore_mfma(
        const ushort_t* __restrict__ xhc, const ushort_t* __restrict__ xlc,
        const ushort_t* __restrict__ eh, const ushort_t* __restrict__ el,
        const float* __restrict__ cc, const int* __restrict__ count,
        float* __restrict__ rv, int* __restrict__ ri) {
    const int cnt = min(*count, XCAP);
    const int m0 = blockIdx.x * 128;
    if (m0 >= cnt) return;
    __shared__ union U {
        struct { short XH[2][128][32]; short XL[2][128][32];
                 short EH[2][128][32]; short EL[2][128][32]; } t;  // 64KB
        struct { float v1[128][2]; int i1[128][2]; } r;
    } sh;
    const int tid = threadIdx.x;

    const int ca0 = tid, ca1 = 256 + tid;
    const int row0 = ca0 >> 2, gq0 = (ca0 & 3) ^ ((ca0 >> 3) & 3);
    const int row1 = ca1 >> 2, gq1 = (ca1 & 3) ^ ((ca1 >> 3) & 3);
    const size_t aoff0 = (size_t)min(m0 + row0, cnt - 1) * DDIM + gq0 * 8;
    const size_t aoff1 = (size_t)min(m0 + row1, cnt - 1) * DDIM + gq1 * 8;

    // stage all 4 tiles for iteration it = nt*8+kk into buffer it&1
    auto stage = [&](int it) {
        const int nt = it >> 3, kk = it & 7, b = it & 1;
        const int n0 = blockIdx.y * 256 + nt * 128;
        const size_t boff0 = (size_t)(n0 + row0) * DDIM + kk * 32 + gq0 * 8;
        const size_t boff1 = (size_t)(n0 + row1) * DDIM + kk * 32 + gq1 * 8;
        const size_t a0 = aoff0 + kk * 32, a1 = aoff1 + kk * 32;
        gload_lds16(xhc + a0, &sh.t.XH[b][0][0] + ca0 * 8);
        gload_lds16(xhc + a1, &sh.t.XH[b][0][0] + ca1 * 8);
        gload_lds16(xlc + a0, &sh.t.XL[b][0][0] + ca0 * 8);
        gload_lds16(xlc + a1, &sh.t.XL[b][0][0] + ca1 * 8);
        gload_lds16(eh + boff0, &sh.t.EH[b][0][0] + ca0 * 8);
        gload_lds16(eh + boff1, &sh.t.EH[b][0][0] + ca1 * 8);
        gload_lds16(el + boff0, &sh.t.EL[b][0][0] + ca0 * 8);
        gload_lds16(el + boff1, &sh.t.EL[b][0][0] + ca1 * 8);
    };

    const int lane = tid & 63, wv = tid >> 6, wr = wv >> 1, wc = wv & 1;
    const int L15 = lane & 15, quad = lane >> 4;
    const int chn = (quad ^ ((L15 >> 1) & 3)) * 16;
    const size_t roff = (size_t)(wr * 64 + L15) * 64 + chn;   // A-side row base
    const size_t coff = (size_t)(wc * 64 + L15) * 64 + chn;   // B-side row base

    float v1[16]; int i1[16];
#pragma unroll
    for (int r2 = 0; r2 < 16; ++r2) { v1[r2] = -3.4e38f; i1[r2] = 0; }

    stage(0);

#pragma unroll 1
    for (int nt = 0; nt < 2; ++nt) {
        const int n0 = blockIdx.y * 256 + nt * 128;
        f32x4 acc[4][4];
#pragma unroll 1
        for (int kk = 0; kk < 8; ++kk) {
            const int it = nt * 8 + kk, b = it & 1;
            __syncthreads();
            if (it + 1 < 16) stage(it + 1);
            const char* XHb = (const char*)&sh.t.XH[b][0][0] + roff;
            const char* XLb = (const char*)&sh.t.XL[b][0][0] + roff;
            const char* EHb = (const char*)&sh.t.EH[b][0][0] + coff;
            const char* ELb = (const char*)&sh.t.EL[b][0][0] + coff;
            if (kk == 0) frag_mfma<true>(XHb, EHb, acc);
            else         frag_mfma<false>(XHb, EHb, acc);
            frag_mfma<false>(XHb, ELb, acc);
            frag_mfma<false>(XLb, EHb, acc);
        }
        const int nb = n0 + wc * 64 + L15;
        float ccv[4];
#pragma unroll
        for (int j = 0; j < 4; ++j) ccv[j] = cc[nb + j * 16];
#pragma unroll
        for (int i = 0; i < 4; ++i)
#pragma unroll
            for (int r = 0; r < 4; ++r) {
                const int row = i * 4 + r;
#pragma unroll
                for (int j = 0; j < 4; ++j) {
                    float u = acc[i][j][r] + ccv[j];
                    int n = nb + j * 16;
                    if (u > v1[row]) { v1[row] = u; i1[row] = n; }
                }
            }
    }
    __syncthreads();
#pragma unroll
    for (int row = 0; row < 16; ++row) {
        float a1 = v1[row]; int ai = i1[row];
#pragma unroll
        for (int off = 1; off < 16; off <<= 1) {
            float o1 = __shfl_xor(a1, off, 64);
            int oi = __shfl_xor(ai, off, 64);
            if (o1 > a1 || (o1 == a1 && oi < ai)) { a1 = o1; ai = oi; }
        }
        if (L15 == 0) {
            int i = row >> 2, r = row & 3;
            int lr = wr * 64 + i * 16 + quad * 4 + r;
            sh.r.v1[lr][wc] = a1; sh.r.i1[lr][wc] = ai;
        }
    }
    __syncthreads();
    if (tid < 128 && m0 + tid < cnt) {
        float av1 = sh.r.v1[tid][0]; int ai1 = sh.r.i1[tid][0];
        float bv1 = sh.r.v1[tid][1]; int bi1 = sh.r.i1[tid][1];
        float o1; int oi;
        if (bv1 > av1 || (bv1 == av1 && bi1 < ai1)) { o1 = bv1; oi = bi1; }
        else { o1 = av1; oi = ai1; }
        size_t o = (size_t)(m0 + tid) * NST + blockIdx.y;
        rv[o] = o1; ri[o] = oi;
    }
}

// ---------------------------------------------------------------------------
// merge tier-2 slices + gather for flagged tokens
// (one wave per token, 4 per wave via grid-stride; grid 1024)
// ---------------------------------------------------------------------------
__global__ __launch_bounds__(256) void vq_merge2_gather(
        const int* __restrict__ wl, const int* __restrict__ count,
        const float* __restrict__ rv, const int* __restrict__ ri,
        const float* __restrict__ embed, float* __restrict__ out) {
    const int wave = threadIdx.x >> 6, lane = threadIdx.x & 63;
    const int cnt = min(*count, XCAP);
#pragma unroll 1
    for (int wi = blockIdx.x * 4 + wave; wi < cnt; wi += 4096) {
        float v1 = -3.4e38f; int i1 = 0x7fffffff;
        if (lane < NST) {
            size_t o = (size_t)wi * NST + lane;
            v1 = rv[o]; i1 = ri[o];
        }
#pragma unroll
        for (int off = 1; off < NST; off <<= 1) {
            float o1 = __shfl_xor(v1, off, 64);
            int oi = __shfl_xor(i1, off, 64);
            if (o1 > v1 || (o1 == v1 && oi < i1)) { v1 = o1; i1 = oi; }
        }
        int idx = __shfl(i1, 0, 64);
        int t = wl[wi];
        const float4* src = (const float4*)(embed + (size_t)idx * DDIM);
        float4* dst = (float4*)(out + (size_t)t * DDIM);
        dst[lane] = src[lane];
    }
}

// ===========================================================================
// Fallback fp32 path (round-1, validated) for small workspace
// ===========================================================================
#define TMF 128
#define DCF 32
#define LSF 132
#define KSPLITF 4
#define KPERF (KCB / KSPLITF)

__global__ __launch_bounds__(256) void vq_e2_fp32(const float* __restrict__ embed,
                                                  float* __restrict__ e2) {
    int k = blockIdx.x * blockDim.x + threadIdx.x;
    if (k >= KCB) return;
    const float4* row = (const float4*)(embed + (size_t)k * DDIM);
    float s = 0.f;
#pragma unroll
    for (int i = 0; i < DDIM / 4; ++i) {
        float4 v = row[i];
        s += v.x * v.x + v.y * v.y + v.z * v.z + v.w * v.w;
    }
    e2[k] = s;
}

__global__ __launch_bounds__(256, 3) void vq_main_fp32(
        const float* __restrict__ x, const float* __restrict__ embed,
        const float* __restrict__ e2,
        float* __restrict__ bestv, int* __restrict__ besti) {
    __shared__ union U {
        struct { float xs[DCF][LSF]; float es[DCF][LSF]; } t;
        struct { float v[TMF][16]; int i[TMF][16]; } r;
    } sh;
    const int tid = threadIdx.x;
    const int tx = tid & 15, ty = tid >> 4;
    const int m0 = blockIdx.x * TMF;
    const int kbase = blockIdx.y * KPERF;
    const int srow = tid >> 3, sd4 = (tid & 7) * 4;
    float bv[2][4]; int bi[2][4];
#pragma unroll
    for (int a = 0; a < 2; ++a)
#pragma unroll
        for (int b = 0; b < 4; ++b) { bv[a][b] = 3.4e38f; bi[a][b] = 0; }
    for (int kt = 0; kt < KPERF / 128; ++kt) {
        const int k0 = kbase + kt * 128;
        float acc[2][4][2][4];
#pragma unroll
        for (int a = 0; a < 2; ++a)
#pragma unroll
            for (int b = 0; b < 4; ++b)
#pragma unroll
                for (int c = 0; c < 2; ++c)
#pragma unroll
                    for (int e = 0; e < 4; ++e) acc[a][b][c][e] = 0.f;
        for (int dc = 0; dc < DDIM / DCF; ++dc) {
#pragma unroll
            for (int p = 0; p < 4; ++p) {
                int m = p * 32 + srow;
                float4 v = *(const float4*)(x + (size_t)(m0 + m) * DDIM + dc * DCF + sd4);
                sh.t.xs[sd4 + 0][m] = v.x; sh.t.xs[sd4 + 1][m] = v.y;
                sh.t.xs[sd4 + 2][m] = v.z; sh.t.xs[sd4 + 3][m] = v.w;
                float4 w = *(const float4*)(embed + (size_t)(k0 + m) * DDIM + dc * DCF + sd4);
                sh.t.es[sd4 + 0][m] = w.x; sh.t.es[sd4 + 1][m] = w.y;
                sh.t.es[sd4 + 2][m] = w.z; sh.t.es[sd4 + 3][m] = w.w;
            }
            __syncthreads();
#pragma unroll 8
            for (int d = 0; d < DCF; ++d) {
                float4 xa0 = *(const float4*)&sh.t.xs[d][ty * 4];
                float4 xa1 = *(const float4*)&sh.t.xs[d][ty * 4 + 64];
                float4 eb0 = *(const float4*)&sh.t.es[d][tx * 4];
                float4 eb1 = *(const float4*)&sh.t.es[d][tx * 4 + 64];
                float xr[2][4] = {{xa0.x, xa0.y, xa0.z, xa0.w}, {xa1.x, xa1.y, xa1.z, xa1.w}};
                float er[2][4] = {{eb0.x, eb0.y, eb0.z, eb0.w}, {eb1.x, eb1.y, eb1.z, eb1.w}};
#pragma unroll
                for (int a = 0; a < 2; ++a)
#pragma unroll
                    for (int b = 0; b < 4; ++b)
#pragma unroll
                        for (int c = 0; c < 2; ++c)
#pragma unroll
                            for (int e = 0; e < 4; ++e)
                                acc[a][b][c][e] += xr[a][b] * er[c][e];
            }
            __syncthreads();
        }
#pragma unroll
        for (int c = 0; c < 2; ++c)
#pragma unroll
            for (int e = 0; e < 4; ++e) {
                int k = k0 + c * 64 + tx * 4 + e;
                float ek = e2[k];
#pragma unroll
                for (int a = 0; a < 2; ++a)
#pragma unroll
                    for (int b = 0; b < 4; ++b) {
                        float s = ek - 2.f * acc[a][b][c][e];
                        if (s < bv[a][b]) { bv[a][b] = s; bi[a][b] = k; }
                    }
            }
    }
    __syncthreads();
#pragma unroll
    for (int a = 0; a < 2; ++a)
#pragma unroll
        for (int b = 0; b < 4; ++b) {
            int row = a * 64 + ty * 4 + b;
            sh.r.v[row][tx] = bv[a][b]; sh.r.i[row][tx] = bi[a][b];
        }
    __syncthreads();
    if (tid < TMF) {
        float best = sh.r.v[tid][0]; int idx = sh.r.i[tid][0];
#pragma unroll
        for (int j = 1; j < 16; ++j) {
            float v = sh.r.v[tid][j]; int ii = sh.r.i[tid][j];
            if (v < best || (v == best && ii < idx)) { best = v; idx = ii; }
        }
        bestv[(size_t)blockIdx.y * NTOK + m0 + tid] = best;
        besti[(size_t)blockIdx.y * NTOK + m0 + tid] = idx;
    }
}

__global__ __launch_bounds__(256) void vq_gather_fp32(
        const float* __restrict__ embed, const float* __restrict__ bestv,
        const int* __restrict__ besti, float* __restrict__ out) {
    int token = blockIdx.x * 4 + (threadIdx.x >> 6);
    int lane = threadIdx.x & 63;
    float best = bestv[token]; int idx = besti[token];
#pragma unroll
    for (int s = 1; s < KSPLITF; ++s) {
        float v = bestv[(size_t)s * NTOK + token];
        int ii = besti[(size_t)s * NTOK + token];
        if (v < best || (v == best && ii < idx)) { best = v; idx = ii; }
    }
    const float4* src = (const float4*)(embed + (size_t)idx * DDIM);
    float4* dst = (float4*)(out + (size_t)token * DDIM);
    dst[lane] = src[lane];
}

// ===========================================================================
extern "C" void kernel_launch(void* const* d_in, const int* in_sizes, int n_in,
                              void* d_out, int out_size, void* d_ws, size_t ws_size,
                              hipStream_t stream) {
    (void)in_sizes; (void)n_in; (void)out_size;
    const float* x = (const float*)d_in[0];
    const float* embed = (const float*)d_in[1];
    float* out = (float*)d_out;

    char* w = (char*)d_ws;
    auto carve = [&](size_t bytes) { char* p = w; w += (bytes + 255) & ~(size_t)255; return p; };

    const size_t sz_eh = (size_t)KCB * DDIM * 2;           // 2 MB
    const size_t sz_xc = (size_t)XCAP * DDIM * 2;          // 8 MB
    const size_t need = 2 * sz_eh + KCB * 4 + 3 * (size_t)NTOK * NSA * 4 +
                        (size_t)XCAP * 4 + 2 * sz_xc + 2 * (size_t)XCAP * NST * 4 + 8192;

    if (ws_size >= need) {
        ushort_t* eh = (ushort_t*)carve(sz_eh);
        ushort_t* el = (ushort_t*)carve(sz_eh);
        float* cc = (float*)carve(KCB * 4);
        float* gv1 = (float*)carve((size_t)NTOK * NSA * 4);
        int* gi1 = (int*)carve((size_t)NTOK * NSA * 4);
        float* gv2 = (float*)carve((size_t)NTOK * NSA * 4);
        int* wl = (int*)carve((size_t)XCAP * 4);
        ushort_t* xhc = (ushort_t*)carve(sz_xc);
        ushort_t* xlc = (ushort_t*)carve(sz_xc);
        float* rv = (float*)carve((size_t)XCAP * NST * 4);
        int* ri = (int*)carve((size_t)XCAP * NST * 4);
        int* count = (int*)carve(256);

        vq_convert_e<<<KCB / 4, 256, 0, stream>>>(embed, eh, el, cc, count);
        vq_pass_a<<<dim3(NTOK / 128, NSA), 256, 0, stream>>>(x, eh, cc, gv1, gi1, gv2);
        vq_merge_gather<<<2048, 256, 0, stream>>>(gv1, gi1, gv2, embed, x,
                                                  out, wl, count, xhc, xlc);
        vq_rescore_mfma<<<dim3(XCAP / 128, NST), 256, 0, stream>>>(
            xhc, xlc, eh, el, cc, count, rv, ri);
        vq_merge2_gather<<<1024, 256, 0, stream>>>(wl, count, rv, ri, embed, out);
    } else {
        float* e2 = (float*)carve(KCB * 4);
        float* bestv = (float*)carve((size_t)KSPLITF * NTOK * 4);
        int* besti = (int*)carve((size_t)KSPLITF * NTOK * 4);
        vq_e2_fp32<<<KCB / 256, 256, 0, stream>>>(embed, e2);
        vq_main_fp32<<<dim3(NTOK / TMF, KSPLITF), 256, 0, stream>>>(x, embed, e2, bestv, besti);
        vq_gather_fp32<<<NTOK / 4, 256, 0, stream>>>(embed, bestv, besti, out);
    }
}

// Round 7
// 215.008 us; speedup vs baseline: 1.2696x; 1.2696x over previous
//
#include <hip/hip_runtime.h>
#include <cstdint>

#define NTOK 32768
#define DDIM 256
#define KCB  4096
#define NSA 4            // n-splits in pass A (1024 codes per block)
#define NST 16           // n-splits in tier-2 (256 codes per block)
#define XCAP 16384       // max flagged tokens (safety cap; expect ~2%)
#define MARGIN_U 0.18f   // on u = dot - e2/2 + 512 scale (s-scale 0.36)

typedef _Float16 half8 __attribute__((ext_vector_type(8)));
typedef float f32x4 __attribute__((ext_vector_type(4)));
typedef unsigned short ushort_t;

// ---------------------------------------------------------------------------
// helpers
// ---------------------------------------------------------------------------
__device__ __forceinline__ ushort_t f2h(float f, float& back) {
    _Float16 h = (_Float16)f;
    back = (float)h;
    union { _Float16 h; ushort_t u; } c; c.h = h; return c.u;
}
__device__ __forceinline__ short h2s(_Float16 h) {
    union { _Float16 h; short s; } c; c.h = h; return c.s;
}
__device__ __forceinline__ void gload_lds16(const void* g, void* l) {
    __builtin_amdgcn_global_load_lds(
        (const __attribute__((address_space(1))) void*)g,
        (__attribute__((address_space(3))) void*)l, 16, 0, 0);
}
template <bool FIRST>
__device__ __forceinline__ void frag_mfma(const char* Ab, const char* Bb, f32x4 (&acc)[4][4]) {
    half8 af[4], bf[4];
#pragma unroll
    for (int i = 0; i < 4; ++i) af[i] = *(const half8*)(Ab + i * 1024);
#pragma unroll
    for (int j = 0; j < 4; ++j) bf[j] = *(const half8*)(Bb + j * 1024);
#pragma unroll
    for (int i = 0; i < 4; ++i)
#pragma unroll
        for (int j = 0; j < 4; ++j) {
            if (FIRST)
                acc[i][j] = __builtin_amdgcn_mfma_f32_16x16x32_f16(
                    af[i], bf[j], (f32x4){0.f, 0.f, 0.f, 0.f}, 0, 0, 0);
            else
                acc[i][j] = __builtin_amdgcn_mfma_f32_16x16x32_f16(
                    af[i], bf[j], acc[i][j], 0, 0, 0);
        }
}
// A-operand from registers: only B read from LDS
template <bool FIRST>
__device__ __forceinline__ void frag_mfma_reg(const half8 (&af)[4], const char* Bb,
                                              f32x4 (&acc)[4][4]) {
    half8 bf[4];
#pragma unroll
    for (int j = 0; j < 4; ++j) bf[j] = *(const half8*)(Bb + j * 1024);
#pragma unroll
    for (int i = 0; i < 4; ++i)
#pragma unroll
        for (int j = 0; j < 4; ++j) {
            if (FIRST)
                acc[i][j] = __builtin_amdgcn_mfma_f32_16x16x32_f16(
                    af[i], bf[j], (f32x4){0.f, 0.f, 0.f, 0.f}, 0, 0, 0);
            else
                acc[i][j] = __builtin_amdgcn_mfma_f32_16x16x32_f16(
                    af[i], bf[j], acc[i][j], 0, 0, 0);
        }
}

// ---------------------------------------------------------------------------
// convert embed -> f16 hi/lo + cc[k] = 512 - 0.5*e2[k]  (wave per row)
// block 0 zeroes count (replaces the hipMemsetAsync dispatch)
// ---------------------------------------------------------------------------
__global__ __launch_bounds__(256) void vq_convert_e(
        const float* __restrict__ embed, ushort_t* __restrict__ hi,
        ushort_t* __restrict__ lo, float* __restrict__ cc,
        int* __restrict__ count) {
    if (blockIdx.x == 0 && threadIdx.x == 0) *count = 0;
    int row = blockIdx.x * 4 + (threadIdx.x >> 6);
    int lane = threadIdx.x & 63;
    size_t off = (size_t)row * DDIM + lane * 4;
    float4 v = *(const float4*)(embed + off);
    float bx, by, bz, bw;
    ushort4 h, l;
    h.x = f2h(v.x, bx); h.y = f2h(v.y, by); h.z = f2h(v.z, bz); h.w = f2h(v.w, bw);
    float t;
    l.x = f2h(v.x - bx, t); l.y = f2h(v.y - by, t);
    l.z = f2h(v.z - bz, t); l.w = f2h(v.w - bw, t);
    *(ushort4*)(hi + off) = h;
    *(ushort4*)(lo + off) = l;
    float s = v.x * v.x + v.y * v.y + v.z * v.z + v.w * v.w;
#pragma unroll
    for (int o = 1; o < 64; o <<= 1) s += __shfl_xor(s, o, 64);
    if (lane == 0) cc[row] = 512.f - 0.5f * s;
}

// ---------------------------------------------------------------------------
// Pass A (round-7): 128 tokens x 1024 codes.
//   A kk0-3 (half the K-dim) -> REGISTERS (Ar[4][4] = 64 VGPR); kk4-7 stays
//   in LDS (region untouched). Freed 32KB (A kk0-3) aliases a 4-deep B ring.
//   Counted-vmcnt barriers keep prefetch loads in flight across barriers:
//     stage = 2 loads, cc = 4 loads (issued at kk==1 after stageB(it+2)):
//     kk==2,3 -> vmcnt(6); kk==7 -> vmcnt(0) (covers it=63 + cc drain);
//     else vmcnt(2).  (round-6 scheme, spill-free register budget this time:
//     ~64 Ar + 64 acc + 32 top2 + misc < 256 combined VGPR/AGPR)
//   MFMA operand values/order identical to round-5 -> bit-identical output.
// ---------------------------------------------------------------------------
__global__ __launch_bounds__(256, 2) void vq_pass_a(
        const float* __restrict__ x, const ushort_t* __restrict__ eh,
        const float* __restrict__ cc,
        float* __restrict__ gv1, int* __restrict__ gi1, float* __restrict__ gv2) {
    __shared__ union U {
        struct { short A[8][128][32]; } a;   // 64KB A; kk0-3 region reused as ring
        struct { short B[4][128][32]; } b;   // 32KB B ring (aliases A kk0-3)
        struct { float v1[128][2]; int i1[128][2]; float v2[128][2]; } r;
    } sh;
    const int tid = threadIdx.x;
    const int m0 = blockIdx.x * 128;
    const int kbase = blockIdx.y * (KCB / NSA);

    const int lane = tid & 63, wv = tid >> 6, wr = wv >> 1, wc = wv & 1;
    const int L15 = lane & 15, quad = lane >> 4;

    const int ca0 = tid, ca1 = 256 + tid;
    const int row0 = ca0 >> 2, q0 = (ca0 & 3) ^ ((ca0 >> 3) & 3);
    const int row1 = ca1 >> 2, q1 = (ca1 & 3) ^ ((ca1 >> 3) & 3);

    auto stageB = [&](int it) {
        int nt = it >> 3, kk = it & 7;
        short* dst = &sh.b.B[it & 3][0][0];
        int n0 = kbase + nt * 128;
        gload_lds16(eh + (size_t)(n0 + row0) * DDIM + kk * 32 + q0 * 8, dst + ca0 * 8);
        gload_lds16(eh + (size_t)(n0 + row1) * DDIM + kk * 32 + q1 * 8, dst + ca1 * 8);
    };

    // ---- stage A: x fp32 -> f16, once per block (swizzled layout) ----
    {
        const int fr = tid >> 6;      // row offset 0..3
        const int f = tid & 63;       // float4 index within row
        const int akk = f >> 3;       // kk block 0..7
        const int rsw = akk & 1;      // row-bit swizzle for this kk block
        short* Aflat = &sh.a.A[0][0][0];
#pragma unroll 4
        for (int s = 0; s < 32; ++s) {
            int row = s * 4 + fr;
            float4 v = *(const float4*)(x + (size_t)(m0 + row) * DDIM + f * 4);
            short4 pk = { h2s((_Float16)v.x), h2s((_Float16)v.y),
                          h2s((_Float16)v.z), h2s((_Float16)v.w) };
            int qp = ((f >> 1) & 3) ^ ((row >> 1) & 3);
            int rowp = row ^ rsw;
            *(short4*)(Aflat + akk * 4096 + rowp * 32 + qp * 8 + (f & 1) * 4) = pk;
        }
    }
    __syncthreads();

    // ---- A kk0-3 -> registers (same swizzled addressing as round-5) ----
    const int chn = (quad ^ ((L15 >> 1) & 3)) * 16;
    const int aoffE = (wr * 64 + L15) * 64 + chn;
    const char* Abase = (const char*)&sh.a.A[0][0][0];
    const char* Ab0e = Abase + aoffE;
    const char* Ab0o = Abase + (aoffE ^ 64);       // kk odd: row-bit flipped
    half8 Ar[4][4];
#pragma unroll
    for (int k2 = 0; k2 < 4; ++k2) {
        const char* Ab = ((k2 & 1) ? Ab0o : Ab0e) + k2 * 8192;
#pragma unroll
        for (int i = 0; i < 4; ++i) Ar[k2][i] = *(const half8*)(Ab + i * 1024);
    }
    __syncthreads();                  // kk0-3 consumed by all waves; ring may write

    stageB(0);
    stageB(1);

    const char* Bb0 = (const char*)&sh.b.B[0][0][0] + (wc * 64 + L15) * 64 + chn;

    float v1p[16], v2p[16];
#pragma unroll
    for (int s = 0; s < 16; ++s) { v1p[s] = -3.4e38f; v2p[s] = -3.4e38f; }

#pragma unroll 1
    for (int nt = 0; nt < 8; ++nt) {
        f32x4 acc[4][4];
        float cc0, cc1, cc2, cc3;
#pragma unroll
        for (int kk = 0; kk < 8; ++kk) {
            const int it = nt * 8 + kk;
            // counted-vmcnt barrier (FIFO): force stage(it) complete while
            // leaving newer prefetch loads in flight.
            if (kk == 7)
                asm volatile("s_waitcnt vmcnt(0)\n\ts_barrier" ::: "memory");
            else if (kk == 2 || kk == 3)
                asm volatile("s_waitcnt vmcnt(6)\n\ts_barrier" ::: "memory");
            else
                asm volatile("s_waitcnt vmcnt(2)\n\ts_barrier" ::: "memory");
            if (it + 2 < 64) stageB(it + 2);
            if (kk == 1) {   // prefetch cc, consumed at epilogue (7 iters later)
                const float* cb = cc + kbase + nt * 128 + wc * 64 + L15;
                cc0 = cb[0]; cc1 = cb[16]; cc2 = cb[32]; cc3 = cb[48];
            }
            const char* Bb = Bb0 + (it & 3) * 8192;
            if (kk == 0)      frag_mfma_reg<true>(Ar[0], Bb, acc);
            else if (kk == 1) frag_mfma_reg<false>(Ar[1], Bb, acc);
            else if (kk == 2) frag_mfma_reg<false>(Ar[2], Bb, acc);
            else if (kk == 3) frag_mfma_reg<false>(Ar[3], Bb, acc);
            else {
                const char* Ab = ((kk & 1) ? Ab0o : Ab0e) + kk * 8192;
                frag_mfma<false>(Ab, Bb, acc);
            }
        }
        // packed top-2 epilogue (maximize u)
#pragma unroll
        for (int i = 0; i < 4; ++i)
#pragma unroll
            for (int r = 0; r < 4; ++r) {
                const int slot = i * 4 + r;
#pragma unroll
                for (int j = 0; j < 4; ++j) {
                    float ccj = (j == 0) ? cc0 : (j == 1) ? cc1 : (j == 2) ? cc2 : cc3;
                    float u = acc[i][j][r] + ccj;
                    unsigned linv = 31u - (unsigned)(nt * 4 + j);
                    float p = __uint_as_float((__float_as_uint(u) & ~31u) | linv);
                    float tmin = fminf(v1p[slot], p);
                    v1p[slot] = fmaxf(v1p[slot], p);
                    v2p[slot] = fmaxf(v2p[slot], tmin);
                }
            }
    }

    __syncthreads();
    // unpack + cross-lane butterfly + cross-wc merge
#pragma unroll
    for (int i = 0; i < 4; ++i)
#pragma unroll
        for (int r = 0; r < 4; ++r) {
            const int slot = i * 4 + r;
            unsigned b1 = __float_as_uint(v1p[slot]);
            int l1 = 31 - (int)(b1 & 31u);
            float a1 = v1p[slot];
            int ai = kbase + (l1 >> 2) * 128 + wc * 64 + (l1 & 3) * 16 + L15;
            float a2 = v2p[slot];
#pragma unroll
            for (int off = 1; off < 16; off <<= 1) {
                float o1 = __shfl_xor(a1, off, 64);
                int oi = __shfl_xor(ai, off, 64);
                float o2 = __shfl_xor(a2, off, 64);
                if (o1 > a1 || (o1 == a1 && oi < ai)) {
                    a2 = fmaxf(a1, o2); a1 = o1; ai = oi;
                } else {
                    a2 = fmaxf(a2, o1);
                }
            }
            if (L15 == 0) {
                int lr = wr * 64 + i * 16 + quad * 4 + r;
                sh.r.v1[lr][wc] = a1; sh.r.i1[lr][wc] = ai; sh.r.v2[lr][wc] = a2;
            }
        }
    __syncthreads();
    if (tid < 128) {
        float av1 = sh.r.v1[tid][0]; int ai1 = sh.r.i1[tid][0]; float av2 = sh.r.v2[tid][0];
        float bv1 = sh.r.v1[tid][1]; int bi1 = sh.r.i1[tid][1]; float bv2 = sh.r.v2[tid][1];
        float o1, o2; int oi;
        if (bv1 > av1 || (bv1 == av1 && bi1 < ai1)) { o1 = bv1; oi = bi1; o2 = fmaxf(av1, bv2); }
        else { o1 = av1; oi = ai1; o2 = fmaxf(av2, bv1); }
        size_t o = (size_t)(m0 + tid) * NSA + blockIdx.y;
        gv1[o] = o1; gi1[o] = oi; gv2[o] = o2;
    }
}

// ---------------------------------------------------------------------------
// merge NSA slices per token; gather clear winners; flag small-gap tokens
// AND compact-convert their x row to f16 hi/lo in the same pass
// (one wave per token, 4 tokens per wave via grid-stride; grid 2048)
// ---------------------------------------------------------------------------
__global__ __launch_bounds__(256) void vq_merge_gather(
        const float* __restrict__ gv1, const int* __restrict__ gi1,
        const float* __restrict__ gv2, const float* __restrict__ embed,
        const float* __restrict__ x,
        float* __restrict__ out, int* __restrict__ wl, int* __restrict__ count,
        ushort_t* __restrict__ xhc, ushort_t* __restrict__ xlc) {
    const int wave = threadIdx.x >> 6, lane = threadIdx.x & 63;
#pragma unroll 1
    for (int t = blockIdx.x * 4 + wave; t < NTOK; t += 8192) {
        float v1 = -3.4e38f, v2 = -3.4e38f; int i1 = 0x7fffffff;
        if (lane < NSA) {
            size_t o = (size_t)t * NSA + lane;
            v1 = gv1[o]; i1 = gi1[o]; v2 = gv2[o];
        }
#pragma unroll
        for (int off = 1; off < NSA; off <<= 1) {
            float o1 = __shfl_xor(v1, off, 64);
            int oi = __shfl_xor(i1, off, 64);
            float o2 = __shfl_xor(v2, off, 64);
            if (o1 > v1 || (o1 == v1 && oi < i1)) { v2 = fmaxf(v1, o2); v1 = o1; i1 = oi; }
            else v2 = fmaxf(v2, o1);
        }
        int flag = __shfl((v1 - v2 < MARGIN_U) ? 1 : 0, 0, 64);
        int idx = __shfl(i1, 0, 64);
        int p = 0x7fffffff;
        if (flag && lane == 0) p = atomicAdd(count, 1);
        p = __shfl(p, 0, 64);
        if (flag && p < XCAP) {
            // compact-convert this token's x row at slot p
            float4 v = *(const float4*)(x + (size_t)t * DDIM + lane * 4);
            float bx, by, bz, bw;
            ushort4 h, l;
            h.x = f2h(v.x, bx); h.y = f2h(v.y, by); h.z = f2h(v.z, bz); h.w = f2h(v.w, bw);
            float tt;
            l.x = f2h(v.x - bx, tt); l.y = f2h(v.y - by, tt);
            l.z = f2h(v.z - bz, tt); l.w = f2h(v.w - bw, tt);
            size_t off2 = (size_t)p * DDIM + lane * 4;
            *(ushort4*)(xhc + off2) = h;
            *(ushort4*)(xlc + off2) = l;
            if (lane == 0) wl[p] = t;
        } else {
            const float4* src = (const float4*)(embed + (size_t)idx * DDIM);
            float4* dst = (float4*)(out + (size_t)t * DDIM);
            dst[lane] = src[lane];
        }
    }
}

// ---------------------------------------------------------------------------
// Tier-2: fused 3-product f16 MFMA rescore over compacted flagged tokens.
// acc = xh*eh + xh*el + xl*eh  (all into one accumulator), so per kk-chunk
// stage all 4 tiles (32KB) once, double-buffered, 48 MFMA per barrier window.
// Grid (XCAP/128, NST). Maximize u = dot + cc.
// ---------------------------------------------------------------------------
__global__ __launch_bounds__(256, 2) void vq_rescore_mfma(
        const ushort_t* __restrict__ xhc, const ushort_t* __restrict__ xlc,
        const ushort_t* __restrict__ eh, const ushort_t* __restrict__ el,
        const float* __restrict__ cc, const int* __restrict__ count,
        float* __restrict__ rv, int* __restrict__ ri) {
    const int cnt = min(*count, XCAP);
    const int m0 = blockIdx.x * 128;
    if (m0 >= cnt) return;
    __shared__ union U {
        struct { short XH[2][128][32]; short XL[2][128][32];
                 short EH[2][128][32]; short EL[2][128][32]; } t;  // 64KB
        struct { float v1[128][2]; int i1[128][2]; } r;
    } sh;
    const int tid = threadIdx.x;

    const int ca0 = tid, ca1 = 256 + tid;
    const int row0 = ca0 >> 2, gq0 = (ca0 & 3) ^ ((ca0 >> 3) & 3);
    const int row1 = ca1 >> 2, gq1 = (ca1 & 3) ^ ((ca1 >> 3) & 3);
    const size_t aoff0 = (size_t)min(m0 + row0, cnt - 1) * DDIM + gq0 * 8;
    const size_t aoff1 = (size_t)min(m0 + row1, cnt - 1) * DDIM + gq1 * 8;

    // stage all 4 tiles for iteration it = nt*8+kk into buffer it&1
    auto stage = [&](int it) {
        const int nt = it >> 3, kk = it & 7, b = it & 1;
        const int n0 = blockIdx.y * 256 + nt * 128;
        const size_t boff0 = (size_t)(n0 + row0) * DDIM + kk * 32 + gq0 * 8;
        const size_t boff1 = (size_t)(n0 + row1) * DDIM + kk * 32 + gq1 * 8;
        const size_t a0 = aoff0 + kk * 32, a1 = aoff1 + kk * 32;
        gload_lds16(xhc + a0, &sh.t.XH[b][0][0] + ca0 * 8);
        gload_lds16(xhc + a1, &sh.t.XH[b][0][0] + ca1 * 8);
        gload_lds16(xlc + a0, &sh.t.XL[b][0][0] + ca0 * 8);
        gload_lds16(xlc + a1, &sh.t.XL[b][0][0] + ca1 * 8);
        gload_lds16(eh + boff0, &sh.t.EH[b][0][0] + ca0 * 8);
        gload_lds16(eh + boff1, &sh.t.EH[b][0][0] + ca1 * 8);
        gload_lds16(el + boff0, &sh.t.EL[b][0][0] + ca0 * 8);
        gload_lds16(el + boff1, &sh.t.EL[b][0][0] + ca1 * 8);
    };

    const int lane = tid & 63, wv = tid >> 6, wr = wv >> 1, wc = wv & 1;
    const int L15 = lane & 15, quad = lane >> 4;
    const int chn = (quad ^ ((L15 >> 1) & 3)) * 16;
    const size_t roff = (size_t)(wr * 64 + L15) * 64 + chn;   // A-side row base
    const size_t coff = (size_t)(wc * 64 + L15) * 64 + chn;   // B-side row base

    float v1[16]; int i1[16];
#pragma unroll
    for (int r2 = 0; r2 < 16; ++r2) { v1[r2] = -3.4e38f; i1[r2] = 0; }

    stage(0);

#pragma unroll 1
    for (int nt = 0; nt < 2; ++nt) {
        const int n0 = blockIdx.y * 256 + nt * 128;
        f32x4 acc[4][4];
#pragma unroll 1
        for (int kk = 0; kk < 8; ++kk) {
            const int it = nt * 8 + kk, b = it & 1;
            __syncthreads();
            if (it + 1 < 16) stage(it + 1);
            const char* XHb = (const char*)&sh.t.XH[b][0][0] + roff;
            const char* XLb = (const char*)&sh.t.XL[b][0][0] + roff;
            const char* EHb = (const char*)&sh.t.EH[b][0][0] + coff;
            const char* ELb = (const char*)&sh.t.EL[b][0][0] + coff;
            if (kk == 0) frag_mfma<true>(XHb, EHb, acc);
            else         frag_mfma<false>(XHb, EHb, acc);
            frag_mfma<false>(XHb, ELb, acc);
            frag_mfma<false>(XLb, EHb, acc);
        }
        const int nb = n0 + wc * 64 + L15;
        float ccv[4];
#pragma unroll
        for (int j = 0; j < 4; ++j) ccv[j] = cc[nb + j * 16];
#pragma unroll
        for (int i = 0; i < 4; ++i)
#pragma unroll
            for (int r = 0; r < 4; ++r) {
                const int row = i * 4 + r;
#pragma unroll
                for (int j = 0; j < 4; ++j) {
                    float u = acc[i][j][r] + ccv[j];
                    int n = nb + j * 16;
                    if (u > v1[row]) { v1[row] = u; i1[row] = n; }
                }
            }
    }
    __syncthreads();
#pragma unroll
    for (int row = 0; row < 16; ++row) {
        float a1 = v1[row]; int ai = i1[row];
#pragma unroll
        for (int off = 1; off < 16; off <<= 1) {
            float o1 = __shfl_xor(a1, off, 64);
            int oi = __shfl_xor(ai, off, 64);
            if (o1 > a1 || (o1 == a1 && oi < ai)) { a1 = o1; ai = oi; }
        }
        if (L15 == 0) {
            int i = row >> 2, r = row & 3;
            int lr = wr * 64 + i * 16 + quad * 4 + r;
            sh.r.v1[lr][wc] = a1; sh.r.i1[lr][wc] = ai;
        }
    }
    __syncthreads();
    if (tid < 128 && m0 + tid < cnt) {
        float av1 = sh.r.v1[tid][0]; int ai1 = sh.r.i1[tid][0];
        float bv1 = sh.r.v1[tid][1]; int bi1 = sh.r.i1[tid][1];
        float o1; int oi;
        if (bv1 > av1 || (bv1 == av1 && bi1 < ai1)) { o1 = bv1; oi = bi1; }
        else { o1 = av1; oi = ai1; }
        size_t o = (size_t)(m0 + tid) * NST + blockIdx.y;
        rv[o] = o1; ri[o] = oi;
    }
}

// ---------------------------------------------------------------------------
// merge tier-2 slices + gather for flagged tokens
// (one wave per token, 4 per wave via grid-stride; grid 1024)
// ---------------------------------------------------------------------------
__global__ __launch_bounds__(256) void vq_merge2_gather(
        const int* __restrict__ wl, const int* __restrict__ count,
        const float* __restrict__ rv, const int* __restrict__ ri,
        const float* __restrict__ embed, float* __restrict__ out) {
    const int wave = threadIdx.x >> 6, lane = threadIdx.x & 63;
    const int cnt = min(*count, XCAP);
#pragma unroll 1
    for (int wi = blockIdx.x * 4 + wave; wi < cnt; wi += 4096) {
        float v1 = -3.4e38f; int i1 = 0x7fffffff;
        if (lane < NST) {
            size_t o = (size_t)wi * NST + lane;
            v1 = rv[o]; i1 = ri[o];
        }
#pragma unroll
        for (int off = 1; off < NST; off <<= 1) {
            float o1 = __shfl_xor(v1, off, 64);
            int oi = __shfl_xor(i1, off, 64);
            if (o1 > v1 || (o1 == v1 && oi < i1)) { v1 = o1; i1 = oi; }
        }
        int idx = __shfl(i1, 0, 64);
        int t = wl[wi];
        const float4* src = (const float4*)(embed + (size_t)idx * DDIM);
        float4* dst = (float4*)(out + (size_t)t * DDIM);
        dst[lane] = src[lane];
    }
}

// ===========================================================================
// Fallback fp32 path (round-1, validated) for small workspace
// ===========================================================================
#define TMF 128
#define DCF 32
#define LSF 132
#define KSPLITF 4
#define KPERF (KCB / KSPLITF)

__global__ __launch_bounds__(256) void vq_e2_fp32(const float* __restrict__ embed,
                                                  float* __restrict__ e2) {
    int k = blockIdx.x * blockDim.x + threadIdx.x;
    if (k >= KCB) return;
    const float4* row = (const float4*)(embed + (size_t)k * DDIM);
    float s = 0.f;
#pragma unroll
    for (int i = 0; i < DDIM / 4; ++i) {
        float4 v = row[i];
        s += v.x * v.x + v.y * v.y + v.z * v.z + v.w * v.w;
    }
    e2[k] = s;
}

__global__ __launch_bounds__(256, 3) void vq_main_fp32(
        const float* __restrict__ x, const float* __restrict__ embed,
        const float* __restrict__ e2,
        float* __restrict__ bestv, int* __restrict__ besti) {
    __shared__ union U {
        struct { float xs[DCF][LSF]; float es[DCF][LSF]; } t;
        struct { float v[TMF][16]; int i[TMF][16]; } r;
    } sh;
    const int tid = threadIdx.x;
    const int tx = tid & 15, ty = tid >> 4;
    const int m0 = blockIdx.x * TMF;
    const int kbase = blockIdx.y * KPERF;
    const int srow = tid >> 3, sd4 = (tid & 7) * 4;
    float bv[2][4]; int bi[2][4];
#pragma unroll
    for (int a = 0; a < 2; ++a)
#pragma unroll
        for (int b = 0; b < 4; ++b) { bv[a][b] = 3.4e38f; bi[a][b] = 0; }
    for (int kt = 0; kt < KPERF / 128; ++kt) {
        const int k0 = kbase + kt * 128;
        float acc[2][4][2][4];
#pragma unroll
        for (int a = 0; a < 2; ++a)
#pragma unroll
            for (int b = 0; b < 4; ++b)
#pragma unroll
                for (int c = 0; c < 2; ++c)
#pragma unroll
                    for (int e = 0; e < 4; ++e) acc[a][b][c][e] = 0.f;
        for (int dc = 0; dc < DDIM / DCF; ++dc) {
#pragma unroll
            for (int p = 0; p < 4; ++p) {
                int m = p * 32 + srow;
                float4 v = *(const float4*)(x + (size_t)(m0 + m) * DDIM + dc * DCF + sd4);
                sh.t.xs[sd4 + 0][m] = v.x; sh.t.xs[sd4 + 1][m] = v.y;
                sh.t.xs[sd4 + 2][m] = v.z; sh.t.xs[sd4 + 3][m] = v.w;
                float4 w = *(const float4*)(embed + (size_t)(k0 + m) * DDIM + dc * DCF + sd4);
                sh.t.es[sd4 + 0][m] = w.x; sh.t.es[sd4 + 1][m] = w.y;
                sh.t.es[sd4 + 2][m] = w.z; sh.t.es[sd4 + 3][m] = w.w;
            }
            __syncthreads();
#pragma unroll 8
            for (int d = 0; d < DCF; ++d) {
                float4 xa0 = *(const float4*)&sh.t.xs[d][ty * 4];
                float4 xa1 = *(const float4*)&sh.t.xs[d][ty * 4 + 64];
                float4 eb0 = *(const float4*)&sh.t.es[d][tx * 4];
                float4 eb1 = *(const float4*)&sh.t.es[d][tx * 4 + 64];
                float xr[2][4] = {{xa0.x, xa0.y, xa0.z, xa0.w}, {xa1.x, xa1.y, xa1.z, xa1.w}};
                float er[2][4] = {{eb0.x, eb0.y, eb0.z, eb0.w}, {eb1.x, eb1.y, eb1.z, eb1.w}};
#pragma unroll
                for (int a = 0; a < 2; ++a)
#pragma unroll
                    for (int b = 0; b < 4; ++b)
#pragma unroll
                        for (int c = 0; c < 2; ++c)
#pragma unroll
                            for (int e = 0; e < 4; ++e)
                                acc[a][b][c][e] += xr[a][b] * er[c][e];
            }
            __syncthreads();
        }
#pragma unroll
        for (int c = 0; c < 2; ++c)
#pragma unroll
            for (int e = 0; e < 4; ++e) {
                int k = k0 + c * 64 + tx * 4 + e;
                float ek = e2[k];
#pragma unroll
                for (int a = 0; a < 2; ++a)
#pragma unroll
                    for (int b = 0; b < 4; ++b) {
                        float s = ek - 2.f * acc[a][b][c][e];
                        if (s < bv[a][b]) { bv[a][b] = s; bi[a][b] = k; }
                    }
            }
    }
    __syncthreads();
#pragma unroll
    for (int a = 0; a < 2; ++a)
#pragma unroll
        for (int b = 0; b < 4; ++b) {
            int row = a * 64 + ty * 4 + b;
            sh.r.v[row][tx] = bv[a][b]; sh.r.i[row][tx] = bi[a][b];
        }
    __syncthreads();
    if (tid < TMF) {
        float best = sh.r.v[tid][0]; int idx = sh.r.i[tid][0];
#pragma unroll
        for (int j = 1; j < 16; ++j) {
            float v = sh.r.v[tid][j]; int ii = sh.r.i[tid][j];
            if (v < best || (v == best && ii < idx)) { best = v; idx = ii; }
        }
        bestv[(size_t)blockIdx.y * NTOK + m0 + tid] = best;
        besti[(size_t)blockIdx.y * NTOK + m0 + tid] = idx;
    }
}

__global__ __launch_bounds__(256) void vq_gather_fp32(
        const float* __restrict__ embed, const float* __restrict__ bestv,
        const int* __restrict__ besti, float* __restrict__ out) {
    int token = blockIdx.x * 4 + (threadIdx.x >> 6);
    int lane = threadIdx.x & 63;
    float best = bestv[token]; int idx = besti[token];
#pragma unroll
    for (int s = 1; s < KSPLITF; ++s) {
        float v = bestv[(size_t)s * NTOK + token];
        int ii = besti[(size_t)s * NTOK + token];
        if (v < best || (v == best && ii < idx)) { best = v; idx = ii; }
    }
    const float4* src = (const float4*)(embed + (size_t)idx * DDIM);
    float4* dst = (float4*)(out + (size_t)token * DDIM);
    dst[lane] = src[lane];
}

// ===========================================================================
extern "C" void kernel_launch(void* const* d_in, const int* in_sizes, int n_in,
                              void* d_out, int out_size, void* d_ws, size_t ws_size,
                              hipStream_t stream) {
    (void)in_sizes; (void)n_in; (void)out_size;
    const float* x = (const float*)d_in[0];
    const float* embed = (const float*)d_in[1];
    float* out = (float*)d_out;

    char* w = (char*)d_ws;
    auto carve = [&](size_t bytes) { char* p = w; w += (bytes + 255) & ~(size_t)255; return p; };

    const size_t sz_eh = (size_t)KCB * DDIM * 2;           // 2 MB
    const size_t sz_xc = (size_t)XCAP * DDIM * 2;          // 8 MB
    const size_t need = 2 * sz_eh + KCB * 4 + 3 * (size_t)NTOK * NSA * 4 +
                        (size_t)XCAP * 4 + 2 * sz_xc + 2 * (size_t)XCAP * NST * 4 + 8192;

    if (ws_size >= need) {
        ushort_t* eh = (ushort_t*)carve(sz_eh);
        ushort_t* el = (ushort_t*)carve(sz_eh);
        float* cc = (float*)carve(KCB * 4);
        float* gv1 = (float*)carve((size_t)NTOK * NSA * 4);
        int* gi1 = (int*)carve((size_t)NTOK * NSA * 4);
        float* gv2 = (float*)carve((size_t)NTOK * NSA * 4);
        int* wl = (int*)carve((size_t)XCAP * 4);
        ushort_t* xhc = (ushort_t*)carve(sz_xc);
        ushort_t* xlc = (ushort_t*)carve(sz_xc);
        float* rv = (float*)carve((size_t)XCAP * NST * 4);
        int* ri = (int*)carve((size_t)XCAP * NST * 4);
        int* count = (int*)carve(256);

        vq_convert_e<<<KCB / 4, 256, 0, stream>>>(embed, eh, el, cc, count);
        vq_pass_a<<<dim3(NTOK / 128, NSA), 256, 0, stream>>>(x, eh, cc, gv1, gi1, gv2);
        vq_merge_gather<<<2048, 256, 0, stream>>>(gv1, gi1, gv2, embed, x,
                                                  out, wl, count, xhc, xlc);
        vq_rescore_mfma<<<dim3(XCAP / 128, NST), 256, 0, stream>>>(
            xhc, xlc, eh, el, cc, count, rv, ri);
        vq_merge2_gather<<<1024, 256, 0, stream>>>(wl, count, rv, ri, embed, out);
    } else {
        float* e2 = (float*)carve(KCB * 4);
        float* bestv = (float*)carve((size_t)KSPLITF * NTOK * 4);
        int* besti = (int*)carve((size_t)KSPLITF * NTOK * 4);
        vq_e2_fp32<<<KCB / 256, 256, 0, stream>>>(embed, e2);
        vq_main_fp32<<<dim3(NTOK / TMF, KSPLITF), 256, 0, stream>>>(x, embed, e2, bestv, besti);
        vq_gather_fp32<<<NTOK / 4, 256, 0, stream>>>(embed, bestv, besti, out);
    }
}